// Round 8
// baseline (595.467 us; speedup 1.0000x reference)
//
#include <hip/hip_runtime.h>

#define DIM   256
#define KCB   8192
#define NTOK  32768
#define NSPLIT 2
#define CPS   4096      // codes per split

using half8 = __attribute__((ext_vector_type(8))) _Float16;
using half4 = __attribute__((ext_vector_type(4))) _Float16;
using f32x4 = __attribute__((ext_vector_type(4))) float;

#define GLOBAL_AS(p) ((const __attribute__((address_space(1))) void*)(p))
#define LDS_AS(p)    ((__attribute__((address_space(3))) void*)(p))

__device__ __forceinline__ void ins2(float v, int i, float& b1v, int& b1i,
                                     float& b2v, int& b2i) {
    bool bet1 = (v < b1v) || (v == b1v && i < b1i);
    bool bet2 = (v < b2v) || (v == b2v && i < b2i);
    if (bet1) { b2v = b1v; b2i = b1i; b1v = v; b1i = i; }
    else if (bet2) { b2v = v; b2i = i; }
}

// ---------------- split fp32 rows into fp16 hi (+ optional lo, + optional norms) ----------------
__global__ __launch_bounds__(256) void k_split(const float* __restrict__ src,
                                               _Float16* __restrict__ hi,
                                               _Float16* __restrict__ lo,
                                               float* __restrict__ norm, int nrows) {
    int row = (int)((blockIdx.x * blockDim.x + threadIdx.x) >> 6);
    int lane = threadIdx.x & 63;
    if (row >= nrows) return;
    float4 v = *(const float4*)&src[(size_t)row * DIM + lane * 4];
    float vv[4] = {v.x, v.y, v.z, v.w};
    half4 hh, hl;
    #pragma unroll
    for (int j = 0; j < 4; ++j) {
        _Float16 h = (_Float16)vv[j];
        hh[j] = h;
        hl[j] = (_Float16)(vv[j] - (float)h);
    }
    *(half4*)&hi[(size_t)row * DIM + lane * 4] = hh;
    if (lo) *(half4*)&lo[(size_t)row * DIM + lane * 4] = hl;
    if (norm) {
        float s = v.x*v.x + v.y*v.y + v.z*v.z + v.w*v.w;
        #pragma unroll
        for (int m = 32; m; m >>= 1) s += __shfl_xor(s, m);
        if (lane == 0) norm[row] = s;
    }
}

// ---------------- z = x @ W^T + b via fp16x3 MFMA, stored as (zh, zl) ----------------
__global__ __launch_bounds__(256) void k_linear(const float* __restrict__ x,
                                                const _Float16* __restrict__ wh,
                                                const _Float16* __restrict__ wl,
                                                const float* __restrict__ bias,
                                                _Float16* __restrict__ zh,
                                                _Float16* __restrict__ zl) {
    const int tid = threadIdx.x;
    const int w = tid >> 6, lane = tid & 63;
    const int col = lane & 15, kg = lane >> 4;
    const int m0 = blockIdx.x * 64;
    const int e0 = w * 64;

    f32x4 acc[4][4];
    #pragma unroll
    for (int mi = 0; mi < 4; ++mi)
        #pragma unroll
        for (int nj = 0; nj < 4; ++nj) acc[mi][nj] = (f32x4){0.f, 0.f, 0.f, 0.f};

    for (int kc = 0; kc < 8; ++kc) {
        half8 ah[4], al[4], bh[4], bl[4];
        #pragma unroll
        for (int mi = 0; mi < 4; ++mi) {
            const float* p = &x[(size_t)(m0 + mi * 16 + col) * DIM + kc * 32 + kg * 8];
            float4 v0 = *(const float4*)p;
            float4 v1 = *(const float4*)(p + 4);
            float vv[8] = {v0.x, v0.y, v0.z, v0.w, v1.x, v1.y, v1.z, v1.w};
            #pragma unroll
            for (int j = 0; j < 8; ++j) {
                _Float16 h = (_Float16)vv[j];
                ah[mi][j] = h;
                al[mi][j] = (_Float16)(vv[j] - (float)h);
            }
        }
        #pragma unroll
        for (int nj = 0; nj < 4; ++nj) {
            size_t off = (size_t)(e0 + nj * 16 + col) * DIM + kc * 32 + kg * 8;
            bh[nj] = *(const half8*)&wh[off];
            bl[nj] = *(const half8*)&wl[off];
        }
        #pragma unroll
        for (int mi = 0; mi < 4; ++mi)
            #pragma unroll
            for (int nj = 0; nj < 4; ++nj) {
                acc[mi][nj] = __builtin_amdgcn_mfma_f32_16x16x32_f16(ah[mi], bh[nj], acc[mi][nj], 0, 0, 0);
                acc[mi][nj] = __builtin_amdgcn_mfma_f32_16x16x32_f16(ah[mi], bl[nj], acc[mi][nj], 0, 0, 0);
                acc[mi][nj] = __builtin_amdgcn_mfma_f32_16x16x32_f16(al[mi], bh[nj], acc[mi][nj], 0, 0, 0);
            }
    }
    #pragma unroll
    for (int nj = 0; nj < 4; ++nj) {
        int e = e0 + nj * 16 + col;
        float bv = bias[e];
        #pragma unroll
        for (int mi = 0; mi < 4; ++mi)
            #pragma unroll
            for (int r = 0; r < 4; ++r) {
                int m = m0 + mi * 16 + kg * 4 + r;
                float zv = acc[mi][nj][r] + bv;
                _Float16 h = (_Float16)zv;
                zh[(size_t)m * DIM + e] = h;
                zl[(size_t)m * DIM + e] = (_Float16)(zv - (float)h);
            }
    }
}

// ---------------- fp16 MFMA distance argmin; A in registers, depth-2 chunk pipeline ----------------
// Block: 256 threads = 4 waves; tile 64 tok x 256 codes, 16 tiles/split, chunk = 256 codes x 32 dims.
// A-fragments ah[8][4] (64 tok x K=256 per wave) REGISTER-RESIDENT, loaded once from global
// (statically indexed: kc loop unrolled; rule #20). No zh LDS tile. LDS = ring of 4 x 16 KB
// chunk buffers (R5-proven conflict-free layout). 64 KB -> 2 blocks/CU.
// Pipeline: at iter c issue stage(c+2) into buf[(c+2)&3] (compile-time: (kc+2)&3), then
// s_waitcnt vmcnt(8) (c landed; c+1, c+2 in flight -- ~2 iterations of slack covers an
// L2-miss/HBM latency), s_barrier, compute. One barrier per iter; ring distance 2 is safe.
// __launch_bounds__(256,1): allocator sizes regs on demand (R2/R6); demand ~250 -> 2 waves/SIMD.
__global__ __launch_bounds__(256, 1) void k_argmin(const _Float16* __restrict__ zh,
                                                   const _Float16* __restrict__ ch,
                                                   const float* __restrict__ cnorm,
                                                   float4* __restrict__ cand) {
    extern __shared__ __align__(16) char smem[];
    const int tid = threadIdx.x;
    const int w = tid >> 6, lane = tid & 63;
    const int col = lane & 15, kg = lane >> 4;
    const int split = blockIdx.x & 1;
    const int m0 = (blockIdx.x >> 1) * 64;

    // ---- A fragments: 64 tok x K=256 for this wave, register-resident (128 VGPRs)
    half8 ah[8][4];
    #pragma unroll
    for (int kc = 0; kc < 8; ++kc)
        #pragma unroll
        for (int mi = 0; mi < 4; ++mi)
            ah[kc][mi] = *(const half8*)&zh[(size_t)(m0 + mi * 16 + col) * DIM + kc * 32 + kg * 8];

    // ---- per-thread staging sources (element offsets into ch), R5-proven swizzled layout:
    // 16B slot s = (r>>1)*8 + (((r&1)*4 + kc4) ^ ((r>>1)&7)); linear LDS dest in thread order,
    // inverse-swizzled global source (both-sides-or-neither).
    size_t eb[4];
    #pragma unroll
    for (int j = 0; j < 4; ++j) {
        int s  = j * 256 + w * 64 + lane;   // 16B slot 0..1023
        int rr = s >> 3, q = s & 7;
        int g2 = q ^ (rr & 7);
        int r  = rr * 2 + (g2 >> 2);        // code row 0..255
        int kc4 = g2 & 3;                   // 16B group within 64B k-slice
        eb[j] = (size_t)(split * CPS + r) * DIM + kc4 * 8;
    }
    // ---- per-thread B-read byte offsets (loop-invariant)
    int bslot[4];
    #pragma unroll
    for (int nj = 0; nj < 4; ++nj) {
        int r = w * 64 + nj * 16 + col;     // code row 0..255 in chunk
        bslot[nj] = (((r >> 1) << 3) + ((((r & 1) << 2) + kg) ^ ((r >> 1) & 7))) << 4;
    }

    auto STAGE = [&](int cc, int buf) {
        int off = (cc >> 3) * (256 * DIM) + (cc & 7) * 32;   // uniform across lanes
        #pragma unroll
        for (int j = 0; j < 4; ++j)
            __builtin_amdgcn_global_load_lds(GLOBAL_AS(ch + eb[j] + off),
                LDS_AS(smem + buf * 16384 + j * 4096 + w * 1024), 16, 0, 0);
    };

    STAGE(0, 0);
    STAGE(1, 1);

    float val[16];
    unsigned pidx[8];
    #pragma unroll
    for (int s = 0; s < 16; ++s) val[s] = 3.4e38f;
    #pragma unroll
    for (int s = 0; s < 8; ++s) pidx[s] = 0xFFFFFFFFu;

    f32x4 acc[4][4];
    #pragma unroll
    for (int mi = 0; mi < 4; ++mi)
        #pragma unroll
        for (int nj = 0; nj < 4; ++nj) acc[mi][nj] = (f32x4){0.f, 0.f, 0.f, 0.f};

    for (int t = 0; t < 16; ++t) {
        #pragma unroll
        for (int kc = 0; kc < 8; ++kc) {
            const int c = t * 8 + kc;
            if (c < 126) {
                STAGE(c + 2, (kc + 2) & 3);
                asm volatile("s_waitcnt vmcnt(8)" ::: "memory");   // chunk c landed; c+1,c+2 in flight
            } else if (c == 126) {
                asm volatile("s_waitcnt vmcnt(4)" ::: "memory");
            } else {
                asm volatile("s_waitcnt vmcnt(0)" ::: "memory");
            }
            __builtin_amdgcn_s_barrier();
            __builtin_amdgcn_sched_barrier(0);   // pin: no ds_read hoisted above the barrier

            const char* bb = smem + (kc & 3) * 16384;
            __builtin_amdgcn_s_setprio(1);
            #pragma unroll
            for (int nj = 0; nj < 4; ++nj) {
                half8 b = *(const half8*)(bb + bslot[nj]);
                #pragma unroll
                for (int mi = 0; mi < 4; ++mi)
                    acc[mi][nj] = __builtin_amdgcn_mfma_f32_16x16x32_f16(ah[kc][mi], b, acc[mi][nj], 0, 0, 0);
            }
            __builtin_amdgcn_s_setprio(0);

            if (kc == 7) {   // tile t complete over K=256: score + reset
                #pragma unroll
                for (int nj = 0; nj < 4; ++nj) {
                    int nl = t * 256 + w * 64 + nj * 16 + col;   // < 4096, fits 16 bits
                    float cn = cnorm[split * CPS + nl];
                    #pragma unroll
                    for (int mi = 0; mi < 4; ++mi)
                        #pragma unroll
                        for (int r2 = 0; r2 < 4; ++r2) {
                            float sc = fmaf(-2.0f, acc[mi][nj][r2], cn);
                            int s = mi * 4 + r2;
                            bool bb2 = sc < val[s];
                            unsigned p = pidx[s >> 1];
                            unsigned np = (s & 1) ? ((p & 0x0000FFFFu) | ((unsigned)nl << 16))
                                                  : ((p & 0xFFFF0000u) | (unsigned)nl);
                            val[s] = bb2 ? sc : val[s];
                            pidx[s >> 1] = bb2 ? np : p;
                        }
                }
                #pragma unroll
                for (int mi = 0; mi < 4; ++mi)
                    #pragma unroll
                    for (int nj = 0; nj < 4; ++nj) acc[mi][nj] = (f32x4){0.f, 0.f, 0.f, 0.f};
            }
        }
    }

    __syncthreads();   // full drain once: LDS quiescent before cbuf aliasing

    // unpack, then top-2 butterfly across the 16 lanes sharing each token row
    float b1[16], b2[16]; int i1[16], i2[16];
    #pragma unroll
    for (int s = 0; s < 16; ++s) {
        unsigned p = pidx[s >> 1];
        int nl = (s & 1) ? (int)(p >> 16) : (int)(p & 0xFFFFu);
        b1[s] = val[s]; i1[s] = split * CPS + nl;
        b2[s] = 3.4e38f; i2[s] = 0x7ffffffe;
    }
    #pragma unroll
    for (int m = 1; m < 16; m <<= 1) {
        #pragma unroll
        for (int s = 0; s < 16; ++s) {
            float p1 = __shfl_xor(b1[s], m); int j1 = __shfl_xor(i1[s], m);
            float p2 = __shfl_xor(b2[s], m); int j2 = __shfl_xor(i2[s], m);
            ins2(p1, j1, b1[s], i1[s], b2[s], i2[s]);
            ins2(p2, j2, b1[s], i1[s], b2[s], i2[s]);
        }
    }
    // per-wave top-2 -> LDS [64 rows][4 w], then cross-wave merge
    float4* cbuf = (float4*)smem;
    if (col == 0) {
        #pragma unroll
        for (int s = 0; s < 16; ++s) {
            int mi = s >> 2, r = s & 3;
            int row = mi * 16 + kg * 4 + r;          // token row 0..63
            float4 v; v.x = b1[s]; v.y = __int_as_float(i1[s]); v.z = b2[s]; v.w = __int_as_float(i2[s]);
            cbuf[row * 4 + w] = v;
        }
    }
    __syncthreads();
    if (tid < 64) {
        float4 a = cbuf[tid * 4 + 0];
        float v1 = a.x; int j1 = __float_as_int(a.y);
        float v2 = a.z; int j2 = __float_as_int(a.w);
        #pragma unroll
        for (int q = 1; q < 4; ++q) {
            float4 bq = cbuf[tid * 4 + q];
            ins2(bq.x, __float_as_int(bq.y), v1, j1, v2, j2);
            ins2(bq.z, __float_as_int(bq.w), v1, j1, v2, j2);
        }
        float4 o; o.x = v1; o.y = __int_as_float(j1); o.z = v2; o.w = __int_as_float(j2);
        cand[(size_t)split * NTOK + m0 + tid] = o;
    }
}

// ---------------- exact fp32 rescore of 4 candidates, gather q, loss partials ----------------
__global__ __launch_bounds__(256) void k_finalize(const _Float16* __restrict__ zh,
                                                  const _Float16* __restrict__ zl,
                                                  const float* __restrict__ cb,
                                                  const float* __restrict__ cnorm,
                                                  const float4* __restrict__ cand,
                                                  float* __restrict__ out,
                                                  float* __restrict__ partials) {
    __shared__ float blk[4];
    const int tid = threadIdx.x;
    const int w = tid >> 6, lane = tid & 63;
    const int token = blockIdx.x * 4 + w;

    int ci[4];
    #pragma unroll
    for (int s = 0; s < NSPLIT; ++s) {
        float4 c = cand[(size_t)s * NTOK + token];
        ci[2 * s]     = __float_as_int(c.y);
        ci[2 * s + 1] = __float_as_int(c.w);
    }

    half4 hv = *(const half4*)&zh[(size_t)token * DIM + lane * 4];
    half4 lv = *(const half4*)&zl[(size_t)token * DIM + lane * 4];
    float z0 = (float)hv[0] + (float)lv[0];
    float z1 = (float)hv[1] + (float)lv[1];
    float z2 = (float)hv[2] + (float)lv[2];
    float z3 = (float)hv[3] + (float)lv[3];

    const float4* cb4 = (const float4*)cb;
    float best = 3.4e38f; int bi = 0x7fffffff;
    #pragma unroll
    for (int j = 0; j < 2 * NSPLIT; ++j) {
        int idx = ci[j];
        float4 e = cb4[(size_t)idx * 64 + lane];
        float d = z0 * e.x + z1 * e.y + z2 * e.z + z3 * e.w;
        #pragma unroll
        for (int m = 32; m; m >>= 1) d += __shfl_xor(d, m);
        float sc = cnorm[idx] - 2.0f * d;
        if (sc < best || (sc == best && idx < bi)) { best = sc; bi = idx; }
    }

    float4 q = cb4[(size_t)bi * 64 + lane];
    *(float4*)&out[(size_t)token * DIM + lane * 4] = q;   // x_recon == q (STE)

    float dx = z0 - q.x, dy = z1 - q.y, dz = z2 - q.z, dw = z3 - q.w;
    float ss = dx*dx + dy*dy + dz*dz + dw*dw;
    #pragma unroll
    for (int m = 32; m; m >>= 1) ss += __shfl_xor(ss, m);
    if (lane == 0) blk[w] = ss;
    __syncthreads();
    if (tid == 0) partials[blockIdx.x] = blk[0] + blk[1] + blk[2] + blk[3];
}

// ---------------- reduce partials, write both losses ----------------
__global__ __launch_bounds__(256) void k_losses(const float* __restrict__ partials,
                                                float* __restrict__ out) {
    __shared__ float red[256];
    float s = 0.0f;
    for (int i = threadIdx.x; i < NTOK / 4; i += 256) s += partials[i];
    red[threadIdx.x] = s;
    __syncthreads();
    for (int off = 128; off; off >>= 1) {
        if ((int)threadIdx.x < off) red[threadIdx.x] += red[threadIdx.x + off];
        __syncthreads();
    }
    if (threadIdx.x == 0) {
        float l = red[0] / (float)((size_t)NTOK * DIM);
        out[(size_t)NTOK * DIM]     = l;  // dictionary_loss
        out[(size_t)NTOK * DIM + 1] = l;  // commitment_loss
    }
}

extern "C" void kernel_launch(void* const* d_in, const int* in_sizes, int n_in,
                              void* d_out, int out_size, void* d_ws, size_t ws_size,
                              hipStream_t stream) {
    const float* x  = (const float*)d_in[0];
    const float* W  = (const float*)d_in[1];
    const float* b  = (const float*)d_in[2];
    const float* cb = (const float*)d_in[3];
    float* out = (float*)d_out;

    char* ws = (char*)d_ws;
    size_t off = 0;
    _Float16* zh = (_Float16*)(ws + off); off += (size_t)NTOK * DIM * 2;     // 16 MB
    _Float16* zl = (_Float16*)(ws + off); off += (size_t)NTOK * DIM * 2;     // 16 MB
    _Float16* ch = (_Float16*)(ws + off); off += (size_t)KCB * DIM * 2;      // 4 MB
    _Float16* wh = (_Float16*)(ws + off); off += (size_t)DIM * DIM * 2;      // 128 KB
    _Float16* wl = (_Float16*)(ws + off); off += (size_t)DIM * DIM * 2;      // 128 KB
    float* cnorm = (float*)(ws + off);    off += (size_t)KCB * 4;            // 32 KB
    float4* cand = (float4*)(ws + off);   off += (size_t)NSPLIT * NTOK * 16; // 1 MB
    float* parts = (float*)(ws + off);

    // allow 64 KB dynamic LDS for k_argmin (host-side, executes at capture time)
    static hipError_t _attr_once = hipFuncSetAttribute(
        reinterpret_cast<const void*>(k_argmin),
        hipFuncAttributeMaxDynamicSharedMemorySize, 65536);
    (void)_attr_once;

    k_split<<<dim3(DIM / 4), 256, 0, stream>>>(W, wh, wl, nullptr, DIM);
    k_split<<<dim3(KCB / 4), 256, 0, stream>>>(cb, ch, nullptr, cnorm, KCB);
    k_linear<<<dim3(NTOK / 64), 256, 0, stream>>>(x, wh, wl, b, zh, zl);
    k_argmin<<<dim3(NTOK / 64 * NSPLIT), 256, 65536, stream>>>(zh, ch, cnorm, cand);
    k_finalize<<<dim3(NTOK / 4), 256, 0, stream>>>(zh, zl, cb, cnorm, cand, out, parts);
    k_losses<<<1, 256, 0, stream>>>(parts, out);
}

// Round 9
// 462.096 us; speedup vs baseline: 1.2886x; 1.2886x over previous
//
#include <hip/hip_runtime.h>

#define DIM   256
#define KCB   8192
#define NTOK  32768
#define NSPLIT 2
#define CPS   4096      // codes per split

using half8 = __attribute__((ext_vector_type(8))) _Float16;
using half4 = __attribute__((ext_vector_type(4))) _Float16;
using f32x4 = __attribute__((ext_vector_type(4))) float;

#define GLOBAL_AS(p) ((const __attribute__((address_space(1))) void*)(p))
#define LDS_AS(p)    ((__attribute__((address_space(3))) void*)(p))

__device__ __forceinline__ void ins2(float v, int i, float& b1v, int& b1i,
                                     float& b2v, int& b2i) {
    bool bet1 = (v < b1v) || (v == b1v && i < b1i);
    bool bet2 = (v < b2v) || (v == b2v && i < b2i);
    if (bet1) { b2v = b1v; b2i = b1i; b1v = v; b1i = i; }
    else if (bet2) { b2v = v; b2i = i; }
}

// ---------------- split fp32 rows into fp16 hi (+ optional lo, + optional norms) ----------------
__global__ __launch_bounds__(256) void k_split(const float* __restrict__ src,
                                               _Float16* __restrict__ hi,
                                               _Float16* __restrict__ lo,
                                               float* __restrict__ norm, int nrows) {
    int row = (int)((blockIdx.x * blockDim.x + threadIdx.x) >> 6);
    int lane = threadIdx.x & 63;
    if (row >= nrows) return;
    float4 v = *(const float4*)&src[(size_t)row * DIM + lane * 4];
    float vv[4] = {v.x, v.y, v.z, v.w};
    half4 hh, hl;
    #pragma unroll
    for (int j = 0; j < 4; ++j) {
        _Float16 h = (_Float16)vv[j];
        hh[j] = h;
        hl[j] = (_Float16)(vv[j] - (float)h);
    }
    *(half4*)&hi[(size_t)row * DIM + lane * 4] = hh;
    if (lo) *(half4*)&lo[(size_t)row * DIM + lane * 4] = hl;
    if (norm) {
        float s = v.x*v.x + v.y*v.y + v.z*v.z + v.w*v.w;
        #pragma unroll
        for (int m = 32; m; m >>= 1) s += __shfl_xor(s, m);
        if (lane == 0) norm[row] = s;
    }
}

// ---------------- z = x @ W^T + b via fp16x3 MFMA, stored as (zh, zl) ----------------
__global__ __launch_bounds__(256) void k_linear(const float* __restrict__ x,
                                                const _Float16* __restrict__ wh,
                                                const _Float16* __restrict__ wl,
                                                const float* __restrict__ bias,
                                                _Float16* __restrict__ zh,
                                                _Float16* __restrict__ zl) {
    const int tid = threadIdx.x;
    const int w = tid >> 6, lane = tid & 63;
    const int col = lane & 15, kg = lane >> 4;
    const int m0 = blockIdx.x * 64;
    const int e0 = w * 64;

    f32x4 acc[4][4];
    #pragma unroll
    for (int mi = 0; mi < 4; ++mi)
        #pragma unroll
        for (int nj = 0; nj < 4; ++nj) acc[mi][nj] = (f32x4){0.f, 0.f, 0.f, 0.f};

    for (int kc = 0; kc < 8; ++kc) {
        half8 ah[4], al[4], bh[4], bl[4];
        #pragma unroll
        for (int mi = 0; mi < 4; ++mi) {
            const float* p = &x[(size_t)(m0 + mi * 16 + col) * DIM + kc * 32 + kg * 8];
            float4 v0 = *(const float4*)p;
            float4 v1 = *(const float4*)(p + 4);
            float vv[8] = {v0.x, v0.y, v0.z, v0.w, v1.x, v1.y, v1.z, v1.w};
            #pragma unroll
            for (int j = 0; j < 8; ++j) {
                _Float16 h = (_Float16)vv[j];
                ah[mi][j] = h;
                al[mi][j] = (_Float16)(vv[j] - (float)h);
            }
        }
        #pragma unroll
        for (int nj = 0; nj < 4; ++nj) {
            size_t off = (size_t)(e0 + nj * 16 + col) * DIM + kc * 32 + kg * 8;
            bh[nj] = *(const half8*)&wh[off];
            bl[nj] = *(const half8*)&wl[off];
        }
        #pragma unroll
        for (int mi = 0; mi < 4; ++mi)
            #pragma unroll
            for (int nj = 0; nj < 4; ++nj) {
                acc[mi][nj] = __builtin_amdgcn_mfma_f32_16x16x32_f16(ah[mi], bh[nj], acc[mi][nj], 0, 0, 0);
                acc[mi][nj] = __builtin_amdgcn_mfma_f32_16x16x32_f16(ah[mi], bl[nj], acc[mi][nj], 0, 0, 0);
                acc[mi][nj] = __builtin_amdgcn_mfma_f32_16x16x32_f16(al[mi], bh[nj], acc[mi][nj], 0, 0, 0);
            }
    }
    #pragma unroll
    for (int nj = 0; nj < 4; ++nj) {
        int e = e0 + nj * 16 + col;
        float bv = bias[e];
        #pragma unroll
        for (int mi = 0; mi < 4; ++mi)
            #pragma unroll
            for (int r = 0; r < 4; ++r) {
                int m = m0 + mi * 16 + kg * 4 + r;
                float zv = acc[mi][nj][r] + bv;
                _Float16 h = (_Float16)zv;
                zh[(size_t)m * DIM + e] = h;
                zl[(size_t)m * DIM + e] = (_Float16)(zv - (float)h);
            }
    }
}

// ---------------- fp16 MFMA distance argmin; WAVE-PRIVATE staging, barrier-free main loop ----------------
// Block: 256 threads = 4 waves; tile 64 tok x 256 codes, 16 tiles/split, chunk = 256 codes x 32 dims.
// KEY: wave w consumes ONLY chunk rows [64w,64w+64) -> wave w stages exactly its own 4 KB of
// each chunk. No cross-wave sharing of B => NO barriers in the main loop. Each wave free-runs:
// {issue STAGE(c+2) -> own-wave vmcnt(8) -> ds_read own region -> MFMA}. Waves desynchronize,
// SIMD always has issuable work; per-wave depth-2 ring covers L2 latency. Ring-3 private bufs:
// write-after-read safe by per-wave program order (compiler lgkmcnt before MFMA retires the
// ds_reads before next STAGE issues).
// A (zh tile, 64 tok x 256 d, 32 KB) shared read-only in LDS; one prologue __syncthreads only.
// LDS = 32K + 3x16K = 80 KB -> exactly 2 blocks/CU (160 KiB). acc[4][4]=64 AGPR, VGPR ~110:
// R6-proven no-spill regime at (256,1).
__global__ __launch_bounds__(256, 1) void k_argmin(const _Float16* __restrict__ zh,
                                                   const _Float16* __restrict__ ch,
                                                   const float* __restrict__ cnorm,
                                                   float4* __restrict__ cand) {
    extern __shared__ __align__(16) char smem[];
    const int tid = threadIdx.x;
    const int w = tid >> 6, lane = tid & 63;
    const int col = lane & 15, kg = lane >> 4;
    const int split = blockIdx.x & 1;
    const int m0 = (blockIdx.x >> 1) * 64;

    // ---- stage zh tile once (cooperative): 64 rows x 512 B, LDS[row][g'] = Z[row][g'^(row&15)]
    {
        char* base = smem + w * 1024;
        #pragma unroll
        for (int j = 0; j < 8; ++j) {
            int s = j * 256 + w * 64 + lane;          // 16B slot 0..2047
            int row = s >> 5;                         // token row 0..63
            int gp = s & 31;                          // LDS 16B group within 512B row
            int g = gp ^ (row & 15);                  // global 16B group
            const _Float16* src = zh + (size_t)(m0 + row) * DIM + g * 8;
            __builtin_amdgcn_global_load_lds(GLOBAL_AS(src), LDS_AS(base + j * 4096), 16, 0, 0);
        }
    }

    // ---- wave-private staging sources: wave w owns chunk rows [64w, 64w+64).
    // Local layout (R5-proven formula, applied per-wave): 16B slot
    // sl = (rl>>1)*8 + (((rl&1)*4 + kc4) ^ ((rl>>1)&7)), rl in [0,64), region = 4 KB.
    // Stage writes local slots sl = j*64+lane linearly; global source inverse-swizzled.
    size_t eb[4];
    #pragma unroll
    for (int j = 0; j < 4; ++j) {
        int sl = j * 64 + lane;             // local 16B slot 0..255
        int rr = sl >> 3, q = sl & 7;
        int g2 = q ^ (rr & 7);
        int rl = rr * 2 + (g2 >> 2);        // local code row 0..63
        int kc4 = g2 & 3;                   // 16B group within 64B k-slice
        eb[j] = (size_t)(split * CPS + w * 64 + rl) * DIM + kc4 * 8;
    }
    // ---- per-thread B-read byte offsets within wave region (loop-invariant)
    int bslot[4];
    #pragma unroll
    for (int nj = 0; nj < 4; ++nj) {
        int rl = nj * 16 + col;             // local code row 0..63
        bslot[nj] = ((((rl >> 1) << 3) + ((((rl & 1) << 2) + kg) ^ ((rl >> 1) & 7))) << 4)
                    + w * 4096;
    }

    auto STAGE = [&](int cc, int buf) {
        int off = (cc >> 3) * (256 * DIM) + (cc & 7) * 32;   // uniform across lanes
        char* dst = smem + 32768 + buf * 16384 + w * 4096;
        #pragma unroll
        for (int j = 0; j < 4; ++j)
            __builtin_amdgcn_global_load_lds(GLOBAL_AS(ch + eb[j] + off),
                                             LDS_AS(dst + j * 1024), 16, 0, 0);
    };

    STAGE(0, 0);
    STAGE(1, 1);

    float val[16];
    unsigned pidx[8];
    #pragma unroll
    for (int s = 0; s < 16; ++s) val[s] = 3.4e38f;
    #pragma unroll
    for (int s = 0; s < 8; ++s) pidx[s] = 0xFFFFFFFFu;

    f32x4 acc[4][4];
    #pragma unroll
    for (int mi = 0; mi < 4; ++mi)
        #pragma unroll
        for (int nj = 0; nj < 4; ++nj) acc[mi][nj] = (f32x4){0.f, 0.f, 0.f, 0.f};

    __syncthreads();   // zh tile visible to all waves (drains prologue loads once)

    const _Float16* zbuf = (const _Float16*)smem;
    int rd = 0, st = 2;
    for (int t = 0; t < 16; ++t) {
        #pragma unroll
        for (int kc = 0; kc < 8; ++kc) {
            const int c = t * 8 + kc;
            if (c < 126) {
                STAGE(c + 2, st);
                asm volatile("s_waitcnt vmcnt(8)" ::: "memory");   // chunk c landed (own wave)
            } else if (c == 126) {
                asm volatile("s_waitcnt vmcnt(4)" ::: "memory");
            } else {
                asm volatile("s_waitcnt vmcnt(0)" ::: "memory");
            }
            __builtin_amdgcn_sched_barrier(0);

            // A fragments from zh tile (K slice kc*32, 16B groups kc*4+kg)
            half8 a[4];
            #pragma unroll
            for (int mi = 0; mi < 4; ++mi) {
                int row = mi * 16 + col;
                int g = kc * 4 + kg;
                a[mi] = *(const half8*)&zbuf[(size_t)row * 256 + ((g ^ (row & 15)) << 3)];
            }
            const char* bb = smem + 32768 + rd * 16384;
            __builtin_amdgcn_s_setprio(1);
            #pragma unroll
            for (int nj = 0; nj < 4; ++nj) {
                half8 b = *(const half8*)(bb + bslot[nj]);
                #pragma unroll
                for (int mi = 0; mi < 4; ++mi)
                    acc[mi][nj] = __builtin_amdgcn_mfma_f32_16x16x32_f16(a[mi], b, acc[mi][nj], 0, 0, 0);
            }
            __builtin_amdgcn_s_setprio(0);

            if (kc == 7) {   // tile t complete over K=256: score + reset
                #pragma unroll
                for (int nj = 0; nj < 4; ++nj) {
                    int nl = t * 256 + w * 64 + nj * 16 + col;   // < 4096, fits 16 bits
                    float cn = cnorm[split * CPS + nl];
                    #pragma unroll
                    for (int mi = 0; mi < 4; ++mi)
                        #pragma unroll
                        for (int r2 = 0; r2 < 4; ++r2) {
                            float sc = fmaf(-2.0f, acc[mi][nj][r2], cn);
                            int s = mi * 4 + r2;
                            bool bb2 = sc < val[s];
                            unsigned p = pidx[s >> 1];
                            unsigned np = (s & 1) ? ((p & 0x0000FFFFu) | ((unsigned)nl << 16))
                                                  : ((p & 0xFFFF0000u) | (unsigned)nl);
                            val[s] = bb2 ? sc : val[s];
                            pidx[s >> 1] = bb2 ? np : p;
                        }
                }
                #pragma unroll
                for (int mi = 0; mi < 4; ++mi)
                    #pragma unroll
                    for (int nj = 0; nj < 4; ++nj) acc[mi][nj] = (f32x4){0.f, 0.f, 0.f, 0.f};
            }
            rd = (rd == 2) ? 0 : rd + 1;
            st = (st == 2) ? 0 : st + 1;
        }
    }

    __syncthreads();   // all waves done with zh tile before cbuf aliasing

    // unpack, then top-2 butterfly across the 16 lanes sharing each token row
    float b1[16], b2[16]; int i1[16], i2[16];
    #pragma unroll
    for (int s = 0; s < 16; ++s) {
        unsigned p = pidx[s >> 1];
        int nl = (s & 1) ? (int)(p >> 16) : (int)(p & 0xFFFFu);
        b1[s] = val[s]; i1[s] = split * CPS + nl;
        b2[s] = 3.4e38f; i2[s] = 0x7ffffffe;
    }
    #pragma unroll
    for (int m = 1; m < 16; m <<= 1) {
        #pragma unroll
        for (int s = 0; s < 16; ++s) {
            float p1 = __shfl_xor(b1[s], m); int j1 = __shfl_xor(i1[s], m);
            float p2 = __shfl_xor(b2[s], m); int j2 = __shfl_xor(i2[s], m);
            ins2(p1, j1, b1[s], i1[s], b2[s], i2[s]);
            ins2(p2, j2, b1[s], i1[s], b2[s], i2[s]);
        }
    }
    // per-wave top-2 -> LDS [64 rows][4 w], then cross-wave merge
    float4* cbuf = (float4*)smem;
    if (col == 0) {
        #pragma unroll
        for (int s = 0; s < 16; ++s) {
            int mi = s >> 2, r = s & 3;
            int row = mi * 16 + kg * 4 + r;          // token row 0..63
            float4 v; v.x = b1[s]; v.y = __int_as_float(i1[s]); v.z = b2[s]; v.w = __int_as_float(i2[s]);
            cbuf[row * 4 + w] = v;
        }
    }
    __syncthreads();
    if (tid < 64) {
        float4 a = cbuf[tid * 4 + 0];
        float v1 = a.x; int j1 = __float_as_int(a.y);
        float v2 = a.z; int j2 = __float_as_int(a.w);
        #pragma unroll
        for (int q = 1; q < 4; ++q) {
            float4 bq = cbuf[tid * 4 + q];
            ins2(bq.x, __float_as_int(bq.y), v1, j1, v2, j2);
            ins2(bq.z, __float_as_int(bq.w), v1, j1, v2, j2);
        }
        float4 o; o.x = v1; o.y = __int_as_float(j1); o.z = v2; o.w = __int_as_float(j2);
        cand[(size_t)split * NTOK + m0 + tid] = o;
    }
}

// ---------------- exact fp32 rescore of 4 candidates, gather q, loss partials ----------------
__global__ __launch_bounds__(256) void k_finalize(const _Float16* __restrict__ zh,
                                                  const _Float16* __restrict__ zl,
                                                  const float* __restrict__ cb,
                                                  const float* __restrict__ cnorm,
                                                  const float4* __restrict__ cand,
                                                  float* __restrict__ out,
                                                  float* __restrict__ partials) {
    __shared__ float blk[4];
    const int tid = threadIdx.x;
    const int w = tid >> 6, lane = tid & 63;
    const int token = blockIdx.x * 4 + w;

    int ci[4];
    #pragma unroll
    for (int s = 0; s < NSPLIT; ++s) {
        float4 c = cand[(size_t)s * NTOK + token];
        ci[2 * s]     = __float_as_int(c.y);
        ci[2 * s + 1] = __float_as_int(c.w);
    }

    half4 hv = *(const half4*)&zh[(size_t)token * DIM + lane * 4];
    half4 lv = *(const half4*)&zl[(size_t)token * DIM + lane * 4];
    float z0 = (float)hv[0] + (float)lv[0];
    float z1 = (float)hv[1] + (float)lv[1];
    float z2 = (float)hv[2] + (float)lv[2];
    float z3 = (float)hv[3] + (float)lv[3];

    const float4* cb4 = (const float4*)cb;
    float best = 3.4e38f; int bi = 0x7fffffff;
    #pragma unroll
    for (int j = 0; j < 2 * NSPLIT; ++j) {
        int idx = ci[j];
        float4 e = cb4[(size_t)idx * 64 + lane];
        float d = z0 * e.x + z1 * e.y + z2 * e.z + z3 * e.w;
        #pragma unroll
        for (int m = 32; m; m >>= 1) d += __shfl_xor(d, m);
        float sc = cnorm[idx] - 2.0f * d;
        if (sc < best || (sc == best && idx < bi)) { best = sc; bi = idx; }
    }

    float4 q = cb4[(size_t)bi * 64 + lane];
    *(float4*)&out[(size_t)token * DIM + lane * 4] = q;   // x_recon == q (STE)

    float dx = z0 - q.x, dy = z1 - q.y, dz = z2 - q.z, dw = z3 - q.w;
    float ss = dx*dx + dy*dy + dz*dz + dw*dw;
    #pragma unroll
    for (int m = 32; m; m >>= 1) ss += __shfl_xor(ss, m);
    if (lane == 0) blk[w] = ss;
    __syncthreads();
    if (tid == 0) partials[blockIdx.x] = blk[0] + blk[1] + blk[2] + blk[3];
}

// ---------------- reduce partials, write both losses ----------------
__global__ __launch_bounds__(256) void k_losses(const float* __restrict__ partials,
                                                float* __restrict__ out) {
    __shared__ float red[256];
    float s = 0.0f;
    for (int i = threadIdx.x; i < NTOK / 4; i += 256) s += partials[i];
    red[threadIdx.x] = s;
    __syncthreads();
    for (int off = 128; off; off >>= 1) {
        if ((int)threadIdx.x < off) red[threadIdx.x] += red[threadIdx.x + off];
        __syncthreads();
    }
    if (threadIdx.x == 0) {
        float l = red[0] / (float)((size_t)NTOK * DIM);
        out[(size_t)NTOK * DIM]     = l;  // dictionary_loss
        out[(size_t)NTOK * DIM + 1] = l;  // commitment_loss
    }
}

extern "C" void kernel_launch(void* const* d_in, const int* in_sizes, int n_in,
                              void* d_out, int out_size, void* d_ws, size_t ws_size,
                              hipStream_t stream) {
    const float* x  = (const float*)d_in[0];
    const float* W  = (const float*)d_in[1];
    const float* b  = (const float*)d_in[2];
    const float* cb = (const float*)d_in[3];
    float* out = (float*)d_out;

    char* ws = (char*)d_ws;
    size_t off = 0;
    _Float16* zh = (_Float16*)(ws + off); off += (size_t)NTOK * DIM * 2;     // 16 MB
    _Float16* zl = (_Float16*)(ws + off); off += (size_t)NTOK * DIM * 2;     // 16 MB
    _Float16* ch = (_Float16*)(ws + off); off += (size_t)KCB * DIM * 2;      // 4 MB
    _Float16* wh = (_Float16*)(ws + off); off += (size_t)DIM * DIM * 2;      // 128 KB
    _Float16* wl = (_Float16*)(ws + off); off += (size_t)DIM * DIM * 2;      // 128 KB
    float* cnorm = (float*)(ws + off);    off += (size_t)KCB * 4;            // 32 KB
    float4* cand = (float4*)(ws + off);   off += (size_t)NSPLIT * NTOK * 16; // 1 MB
    float* parts = (float*)(ws + off);

    // allow 80 KB dynamic LDS for k_argmin (host-side, executes at capture time)
    static hipError_t _attr_once = hipFuncSetAttribute(
        reinterpret_cast<const void*>(k_argmin),
        hipFuncAttributeMaxDynamicSharedMemorySize, 81920);
    (void)_attr_once;

    k_split<<<dim3(DIM / 4), 256, 0, stream>>>(W, wh, wl, nullptr, DIM);
    k_split<<<dim3(KCB / 4), 256, 0, stream>>>(cb, ch, nullptr, cnorm, KCB);
    k_linear<<<dim3(NTOK / 64), 256, 0, stream>>>(x, wh, wl, b, zh, zl);
    k_argmin<<<dim3(NTOK / 64 * NSPLIT), 256, 81920, stream>>>(zh, ch, cnorm, cand);
    k_finalize<<<dim3(NTOK / 4), 256, 0, stream>>>(zh, zl, cb, cnorm, cand, out, parts);
    k_losses<<<1, 256, 0, stream>>>(parts, out);
}